// Round 1
// baseline (4487.375 us; speedup 1.0000x reference)
//
#include <hip/hip_runtime.h>

// ---------------------------------------------------------------------------
// SuperpixelEbli, CV=32. Branches processed SEQUENTIALLY reusing one buffer
// set sized for the largest branch -> peak workspace 157.4 MB (+4KB bcur)
// (r5's 341 MB layout faulted; r1 proved ~161.5 MB is backed).
// Per branch: CSR build = hist + 2-level scan + TWO-LEVEL scatter:
//   kbucket: edges -> bucket-major tmp (bucket = 512 rows; <=1024 sequential
//            write streams so line fills complete in L2, ~1x amplification;
//            old single-level kfill had 524K open streams -> 16x write amp,
//            269 MB WRITE_SIZE, 400us on branch 1)
//   kplace:  one WG per bucket, per-row cursors in LDS, scatter ei within the
//            bucket's ~16-32KB CSR window (cache-local, no global atomics)
//   tmp lives in the H region (idle during CSR build) -> no extra workspace.
// Then: Z = X@W1^T; 3x { H = A@Z (gather); H += b; readout S[g] via LDS
//   per-graph partials; Z = leaky(H)@Wnext }; classifier + softmax.
// ---------------------------------------------------------------------------

namespace {
constexpr int kG = 512;
constexpr int kNmax = 524288;
constexpr int kEmax = 4194304;

// workspace layout (bytes); peak ~157.4 MB
constexpr size_t OFF_RP  = 0;                               // kNmax int
constexpr size_t OFF_CUR = OFF_RP + (size_t)kNmax * 4;      // kNmax int (row ends)
constexpr size_t OFF_DEG = OFF_CUR + (size_t)kNmax * 4;     // kNmax int
constexpr size_t OFF_BS  = OFF_DEG + (size_t)kNmax * 4;     // 1024 int (scan block sums)
constexpr size_t OFF_BC  = OFF_BS + 4096;                   // 1024 int (bucket cursors)
constexpr size_t OFF_EI  = OFF_BC + 4096;                   // kEmax int
constexpr size_t OFF_Z   = OFF_EI + (size_t)kEmax * 4;      // kNmax*32 f32
constexpr size_t OFF_H   = OFF_Z + (size_t)kNmax * 128;     // kNmax*32 f32 (also tmp for kbucket)
constexpr size_t OFF_S   = OFF_H + (size_t)kNmax * 128;     // 3*512*10 f32
constexpr size_t OFF_CNT = OFF_S + (size_t)3 * kG * 10 * 4; // 3*512 f32
}  // namespace

__device__ __forceinline__ void atomAddF(float* p, float v) {
  __hip_atomic_fetch_add(p, v, __ATOMIC_RELAXED, __HIP_MEMORY_SCOPE_AGENT);
}

// ---------------- CSR build (single branch, local indices) ----------------

__global__ void khist(const int* __restrict__ rows, int* __restrict__ deg) {
  int e = blockIdx.x * 256 + threadIdx.x;
  atomicAdd(&deg[rows[e]], 1);
}

__global__ void kscan1(const int* __restrict__ deg, int* __restrict__ bsums) {
  __shared__ int red[256];
  int t = threadIdx.x;
  int i0 = blockIdx.x * 512 + t * 2;
  red[t] = deg[i0] + deg[i0 + 1];
  __syncthreads();
  for (int st = 128; st; st >>= 1) {
    if (t < st) red[t] += red[t + st];
    __syncthreads();
  }
  if (t == 0) bsums[blockIdx.x] = red[0];
}

// single block, 1024 threads: exclusive scan of bsums[0..len)
__global__ void kscan2(int* __restrict__ bsums, int len) {
  __shared__ int sA[1024], sB[1024];
  int t = threadIdx.x;
  int v = (t < len) ? bsums[t] : 0;
  sA[t] = v;
  __syncthreads();
  int* src = sA;
  int* dst = sB;
  for (int off = 1; off < 1024; off <<= 1) {
    int x = src[t];
    if (t >= off) x += src[t - off];
    dst[t] = x;
    __syncthreads();
    int* tmp = src; src = dst; dst = tmp;
  }
  if (t < len) bsums[t] = src[t] - v;  // exclusive
}

// rowptr = starts, cursor = ENDS (kspmm rowend); bcur = bucket base cursors
__global__ void kscan3(const int* __restrict__ deg, const int* __restrict__ bsums,
                       int* __restrict__ rowptr, int* __restrict__ cursor,
                       int* __restrict__ bcur) {
  __shared__ int sA[256], sB[256];
  int t = threadIdx.x;
  int i0 = blockIdx.x * 512 + t * 2;
  int a = deg[i0], b = deg[i0 + 1];
  int s = a + b;
  sA[t] = s;
  __syncthreads();
  int* src = sA;
  int* dst = sB;
  for (int off = 1; off < 256; off <<= 1) {
    int x = src[t];
    if (t >= off) x += src[t - off];
    dst[t] = x;
    __syncthreads();
    int* tmp = src; src = dst; dst = tmp;
  }
  int excl = src[t] - s;
  int r0 = bsums[blockIdx.x] + excl;
  rowptr[i0] = r0;
  rowptr[i0 + 1] = r0 + a;
  cursor[i0] = r0 + a;          // end of row i0
  cursor[i0 + 1] = r0 + a + b;  // end of row i0+1
  if (t == 0) bcur[blockIdx.x] = r0;  // bucket (=512 rows = this block) base
}

// phase 1: scatter edges to bucket-major tmp. bucket = row>>9; payload packs
// (row&511)<<22 | e  (E<=2^22, 9+22=31 bits). <=1024 sequential write streams.
__global__ void kbucket(const int* __restrict__ rows, int* __restrict__ bcur,
                        int* __restrict__ tmp) {
  int e = blockIdx.x * 256 + threadIdx.x;
  int r = rows[e];
  int p = atomicAdd(&bcur[r >> 9], 1);
  tmp[p] = ((r & 511) << 22) | e;
}

// phase 2: one WG per bucket; per-row cursors in LDS; scatter ei within the
// bucket's contiguous CSR window (~16-32KB -> line-local writes).
__global__ void kplace(const int* __restrict__ tmp, const int* __restrict__ rowptr,
                       int* __restrict__ ei, int nbk, int E) {
  __shared__ int lcur[512];
  int b = blockIdx.x;
  int t = threadIdx.x;
  int rbase = b * 512;
  for (int r = t; r < 512; r += 256) lcur[r] = rowptr[rbase + r];
  __syncthreads();
  int segStart = rowptr[rbase];
  int segEnd = (b == nbk - 1) ? E : rowptr[rbase + 512];
  for (int p = segStart + t; p < segEnd; p += 256) {
    int pk = tmp[p];
    int pos = atomicAdd(&lcur[pk >> 22], 1);
    ei[pos] = pk & 0x3FFFFF;
  }
}

// ---------------- dense / sparse passes (single branch) ----------------

// Z = X @ W^T   (X: n x 32, W: 32 x 32), no bias
__global__ void kproj(const float* __restrict__ X, const float* __restrict__ W,
                      float* __restrict__ Z) {
  __shared__ float w[1024];
  for (int k = threadIdx.x; k < 1024; k += 256) w[k] = W[k];
  __syncthreads();
  int i = blockIdx.x * 256 + threadIdx.x;
  float x[32];
  const float4* xp = (const float4*)(X + (size_t)i * 32);
#pragma unroll
  for (int q = 0; q < 8; q++) {
    float4 t = xp[q];
    x[4 * q] = t.x; x[4 * q + 1] = t.y; x[4 * q + 2] = t.z; x[4 * q + 3] = t.w;
  }
  float z[32];
#pragma unroll
  for (int o = 0; o < 32; o++) {
    float a = 0.f;
#pragma unroll
    for (int f = 0; f < 32; f++) a += w[o * 32 + f] * x[f];
    z[o] = a;
  }
  float4* zr = (float4*)(Z + (size_t)i * 32);
#pragma unroll
  for (int q = 0; q < 8; q++)
    zr[q] = make_float4(z[4 * q], z[4 * q + 1], z[4 * q + 2], z[4 * q + 3]);
}

// H[i] = sum_p vals[ei] * Z[cols[ei]]   (CSR gather; rows with deg 0 -> 0)
__global__ void kspmm(const int* __restrict__ ei, const int* __restrict__ cols,
                      const float* __restrict__ vals, const int* __restrict__ rowptr,
                      const int* __restrict__ rowend, const float* __restrict__ Z,
                      float* __restrict__ H) {
  int gi = blockIdx.x * 256 + threadIdx.x;
  int s = rowptr[gi], e = rowend[gi];
  float acc[32];
#pragma unroll
  for (int j = 0; j < 32; j++) acc[j] = 0.f;
  for (int p = s; p < e; p++) {
    int ed = ei[p];
    int c = cols[ed];
    float v = vals[ed];
    const float4* zr = (const float4*)(Z + (size_t)c * 32);
#pragma unroll
    for (int q = 0; q < 8; q++) {
      float4 t = zr[q];
      acc[4 * q] += v * t.x; acc[4 * q + 1] += v * t.y;
      acc[4 * q + 2] += v * t.z; acc[4 * q + 3] += v * t.w;
    }
  }
  float4* hr = (float4*)(H + (size_t)gi * 32);
#pragma unroll
  for (int q = 0; q < 8; q++)
    hr[q] = make_float4(acc[4 * q], acc[4 * q + 1], acc[4 * q + 2], acc[4 * q + 3]);
}

// H += b (store biased h_l); S[g][o] += h @ Wl[o, 32l:32l+32]; cnt[g] += 1 (l==0)
// LDS per-graph partials (batch sorted => block spans few graphs); fallback to
// direct global atomics if a block spans >8 graphs.
__global__ void kpost(float* __restrict__ H, const float* __restrict__ b,
                      const float* __restrict__ Wl, int l,
                      const int* __restrict__ batch, float* __restrict__ S,
                      float* __restrict__ cnt, int docnt) {
  __shared__ float w[320];      // w[o*32+j] = Wl[o][32l+j]
  __shared__ float bb[32];
  __shared__ float part[8][10];
  __shared__ int pcnt[8];
  __shared__ int g0s;
  int t = threadIdx.x;
  for (int k = t; k < 320; k += 256)
    w[k] = Wl[(k / 32) * 96 + 32 * l + (k % 32)];
  if (t < 32) bb[t] = b[t];
  if (t < 80) part[t / 10][t % 10] = 0.f;
  if (t < 8) pcnt[t] = 0;
  if (t == 0) g0s = batch[blockIdx.x * 256];
  __syncthreads();
  int g0 = g0s;
  int i = blockIdx.x * 256 + t;
  int g = batch[i];
  float4* hp = (float4*)(H + (size_t)i * 32);
  float h[32];
#pragma unroll
  for (int q = 0; q < 8; q++) {
    float4 tq = hp[q];
    h[4 * q] = tq.x + bb[4 * q];         h[4 * q + 1] = tq.y + bb[4 * q + 1];
    h[4 * q + 2] = tq.z + bb[4 * q + 2]; h[4 * q + 3] = tq.w + bb[4 * q + 3];
    hp[q] = make_float4(h[4 * q], h[4 * q + 1], h[4 * q + 2], h[4 * q + 3]);
  }
  float r[10];
#pragma unroll
  for (int o = 0; o < 10; o++) {
    float a = 0.f;
#pragma unroll
    for (int j = 0; j < 32; j++) a += w[o * 32 + j] * h[j];
    r[o] = a;
  }
  int gl = g - g0;
  if (gl >= 0 && gl < 8) {
#pragma unroll
    for (int o = 0; o < 10; o++) atomicAdd(&part[gl][o], r[o]);
    if (docnt) atomicAdd(&pcnt[gl], 1);
  } else {
#pragma unroll
    for (int o = 0; o < 10; o++) atomAddF(&S[(size_t)g * 10 + o], r[o]);
    if (docnt) atomAddF(&cnt[g], 1.f);
  }
  __syncthreads();
  if (t < 80) {
    int gl2 = t / 10, o = t % 10;
    int gg = g0 + gl2;
    float v = part[gl2][o];
    if (gg < kG && v != 0.f) atomAddF(&S[(size_t)gg * 10 + o], v);
  }
  if (docnt && t < 8) {
    int gg = g0 + t;
    if (gg < kG && pcnt[t] > 0) atomAddF(&cnt[gg], (float)pcnt[t]);
  }
}

// Z = leaky(H) @ W^T  (row-local; overwrites Z in place)
__global__ void kmid(const float* __restrict__ H, const float* __restrict__ W,
                     float* __restrict__ Z) {
  __shared__ float w[1024];
  for (int k = threadIdx.x; k < 1024; k += 256) w[k] = W[k];
  __syncthreads();
  int i = blockIdx.x * 256 + threadIdx.x;
  float h[32];
  const float4* hp = (const float4*)(H + (size_t)i * 32);
#pragma unroll
  for (int q = 0; q < 8; q++) {
    float4 t = hp[q];
    h[4 * q] = t.x; h[4 * q + 1] = t.y; h[4 * q + 2] = t.z; h[4 * q + 3] = t.w;
  }
#pragma unroll
  for (int j = 0; j < 32; j++) h[j] = (h[j] >= 0.f) ? h[j] : 0.01f * h[j];
  float z[32];
#pragma unroll
  for (int o = 0; o < 32; o++) {
    float a = 0.f;
#pragma unroll
    for (int f = 0; f < 32; f++) a += w[o * 32 + f] * h[f];
    z[o] = a;
  }
  float4* zr = (float4*)(Z + (size_t)i * 32);
#pragma unroll
  for (int q = 0; q < 8; q++)
    zr[q] = make_float4(z[4 * q], z[4 * q + 1], z[4 * q + 2], z[4 * q + 3]);
}

// out = softmax(concat(S_b / max(cnt_b,1)) @ Wc^T + bc)   Wc: (10,30)
__global__ void kfinal(const float* __restrict__ S, const float* __restrict__ cnt,
                       const float* __restrict__ Wc, const float* __restrict__ bc,
                       float* __restrict__ out) {
  int g = threadIdx.x;  // 512 threads, one per graph
  float o[30];
#pragma unroll
  for (int s = 0; s < 3; s++) {
    float c = cnt[s * kG + g];
    float inv = 1.f / fmaxf(c, 1.f);
#pragma unroll
    for (int j = 0; j < 10; j++)
      o[s * 10 + j] = S[((size_t)s * kG + g) * 10 + j] * inv;
  }
  float z[10];
  float m = -1e30f;
#pragma unroll
  for (int k = 0; k < 10; k++) {
    float t = bc[k];
    for (int j = 0; j < 30; j++) t += Wc[k * 30 + j] * o[j];
    z[k] = t;
    m = fmaxf(m, t);
  }
  float sum = 0.f;
#pragma unroll
  for (int k = 0; k < 10; k++) { z[k] = expf(z[k] - m); sum += z[k]; }
  float r = 1.f / sum;
#pragma unroll
  for (int k = 0; k < 10; k++) out[(size_t)g * 10 + k] = z[k] * r;
}

extern "C" void kernel_launch(void* const* d_in, const int* in_sizes, int n_in,
                              void* d_out, int out_size, void* d_ws, size_t ws_size,
                              hipStream_t stream) {
  const int nb[3] = {262144, 524288, 131072};
  const int eb[3] = {2097152, 4194304, 1048576};

  const int* rowsv[3] = {(const int*)d_in[0], (const int*)d_in[5], (const int*)d_in[10]};
  const int* colsv[3] = {(const int*)d_in[1], (const int*)d_in[6], (const int*)d_in[11]};
  const float* valsv[3] = {(const float*)d_in[2], (const float*)d_in[7], (const float*)d_in[12]};
  const float* Xv[3] = {(const float*)d_in[3], (const float*)d_in[8], (const float*)d_in[13]};
  const int* batchv[3] = {(const int*)d_in[4], (const int*)d_in[9], (const int*)d_in[14]};
  // per-branch weights: W1,b1,W2,b2,W3,b3,Wl,bl at [15..22], [23..30], [31..38]
  const float* W1v[3] = {(const float*)d_in[15], (const float*)d_in[23], (const float*)d_in[31]};
  const float* B1v[3] = {(const float*)d_in[16], (const float*)d_in[24], (const float*)d_in[32]};
  const float* W2v[3] = {(const float*)d_in[17], (const float*)d_in[25], (const float*)d_in[33]};
  const float* B2v[3] = {(const float*)d_in[18], (const float*)d_in[26], (const float*)d_in[34]};
  const float* W3v[3] = {(const float*)d_in[19], (const float*)d_in[27], (const float*)d_in[35]};
  const float* B3v[3] = {(const float*)d_in[20], (const float*)d_in[28], (const float*)d_in[36]};
  const float* Wlv[3] = {(const float*)d_in[21], (const float*)d_in[29], (const float*)d_in[37]};
  const float* Wc = (const float*)d_in[39];
  const float* bc = (const float*)d_in[40];

  char* ws = (char*)d_ws;
  int* rowptr = (int*)(ws + OFF_RP);
  int* cursor = (int*)(ws + OFF_CUR);
  int* deg = (int*)(ws + OFF_DEG);
  int* bsums = (int*)(ws + OFF_BS);
  int* bcur = (int*)(ws + OFF_BC);
  int* ei = (int*)(ws + OFF_EI);
  float* Z = (float*)(ws + OFF_Z);
  float* H = (float*)(ws + OFF_H);
  float* S = (float*)(ws + OFF_S);
  float* cnt = (float*)(ws + OFF_CNT);
  float* out = (float*)d_out;

  hipMemsetAsync(S, 0, (size_t)3 * kG * 10 * 4 + (size_t)3 * kG * 4, stream);

  for (int b = 0; b < 3; b++) {
    const int n = nb[b], e = eb[b];
    const float* Bl[3] = {B1v[b], B2v[b], B3v[b]};
    const float* Wmid[2] = {W2v[b], W3v[b]};
    int* tmp = (int*)(ws + OFF_H);  // H region idle during CSR build

    // CSR build (local indices), two-level scatter
    hipMemsetAsync(deg, 0, (size_t)n * 4, stream);
    khist<<<e / 256, 256, 0, stream>>>(rowsv[b], deg);
    kscan1<<<n / 512, 256, 0, stream>>>(deg, bsums);
    kscan2<<<1, 1024, 0, stream>>>(bsums, n / 512);
    kscan3<<<n / 512, 256, 0, stream>>>(deg, bsums, rowptr, cursor, bcur);
    kbucket<<<e / 256, 256, 0, stream>>>(rowsv[b], bcur, tmp);
    kplace<<<n / 512, 256, 0, stream>>>(tmp, rowptr, ei, n / 512, e);

    // layer 1 projection
    kproj<<<n / 256, 256, 0, stream>>>(Xv[b], W1v[b], Z);

    for (int l = 0; l < 3; l++) {
      kspmm<<<n / 256, 256, 0, stream>>>(ei, colsv[b], valsv[b], rowptr, cursor, Z, H);
      kpost<<<n / 256, 256, 0, stream>>>(H, Bl[l], Wlv[b], l, batchv[b],
                                         S + (size_t)b * kG * 10, cnt + b * kG,
                                         l == 0 ? 1 : 0);
      if (l < 2)
        kmid<<<n / 256, 256, 0, stream>>>(H, Wmid[l], Z);
    }
  }

  kfinal<<<1, 512, 0, stream>>>(S, cnt, Wc, bc, out);
}

// Round 2
// 2695.875 us; speedup vs baseline: 1.6645x; 1.6645x over previous
//
#include <hip/hip_runtime.h>

// ---------------------------------------------------------------------------
// SuperpixelEbli, CV=32. Branches processed SEQUENTIALLY reusing one buffer
// set sized for the largest branch -> peak workspace ~157.4 MB.
// CSR build is a DETERMINISTIC two-level radix partition (no global atomics):
//   khist/kscan1/2/3: per-row degrees -> rowptr (starts) + cursor (ends)
//   kphist:   256 blocks x LDS histogram over NB=n/128 buckets -> cnts[b][k]
//             (cnts lives in idle Z region, <=4MB)
//   kpscan1:  per-bucket exclusive scan over the 256 blocks (bases come free
//             from rowptr[k*128], no extra scan, no contention)
//   kpscatter:re-read chunk, LDS cursors, write (row&127)<<22|e to bucket-
//             major tmp (16MB total -> fits 32MB aggregate L2, ~1x write amp)
//   kplace:   1 WG per 128-row bucket, per-row cursors in LDS, scatter ei
//             within the bucket's ~4KB CSR window (cache-local).
//   History: r0 kfill (524K streams) = 16x write amp, 269MB WRITE, 400us;
//            r1 kbucket (1024-ctr global atomics) = 4096/addr contention,
//            826us. This version has ZERO global atomics in the fill path.
// Then: Z = X@W1^T; 3x { H = A@Z (gather); H += b; readout S[g] via LDS
//   per-graph partials; Z = leaky(H)@Wnext }; classifier + softmax.
// ---------------------------------------------------------------------------

namespace {
constexpr int kG = 512;
constexpr int kNmax = 524288;
constexpr int kEmax = 4194304;
constexpr int kNCH = 256;  // partition chunks (blocks)

// workspace layout (bytes); peak ~157.4 MB
constexpr size_t OFF_RP  = 0;                               // kNmax int
constexpr size_t OFF_CUR = OFF_RP + (size_t)kNmax * 4;      // kNmax int (row ends)
constexpr size_t OFF_DEG = OFF_CUR + (size_t)kNmax * 4;     // kNmax int
constexpr size_t OFF_BS  = OFF_DEG + (size_t)kNmax * 4;     // 1024 int (scan block sums)
constexpr size_t OFF_BC  = OFF_BS + 4096;                   // 1024 int (unused, kept for layout)
constexpr size_t OFF_EI  = OFF_BC + 4096;                   // kEmax int
constexpr size_t OFF_Z   = OFF_EI + (size_t)kEmax * 4;      // kNmax*32 f32 (cnts during build)
constexpr size_t OFF_H   = OFF_Z + (size_t)kNmax * 128;     // kNmax*32 f32 (tmp during build)
constexpr size_t OFF_S   = OFF_H + (size_t)kNmax * 128;     // 3*512*10 f32
constexpr size_t OFF_CNT = OFF_S + (size_t)3 * kG * 10 * 4; // 3*512 f32
}  // namespace

__device__ __forceinline__ void atomAddF(float* p, float v) {
  __hip_atomic_fetch_add(p, v, __ATOMIC_RELAXED, __HIP_MEMORY_SCOPE_AGENT);
}

// ---------------- row-level degree/scan (unchanged) ----------------

__global__ void khist(const int* __restrict__ rows, int* __restrict__ deg) {
  int e = blockIdx.x * 256 + threadIdx.x;
  atomicAdd(&deg[rows[e]], 1);
}

__global__ void kscan1(const int* __restrict__ deg, int* __restrict__ bsums) {
  __shared__ int red[256];
  int t = threadIdx.x;
  int i0 = blockIdx.x * 512 + t * 2;
  red[t] = deg[i0] + deg[i0 + 1];
  __syncthreads();
  for (int st = 128; st; st >>= 1) {
    if (t < st) red[t] += red[t + st];
    __syncthreads();
  }
  if (t == 0) bsums[blockIdx.x] = red[0];
}

// single block, 1024 threads: exclusive scan of bsums[0..len)
__global__ void kscan2(int* __restrict__ bsums, int len) {
  __shared__ int sA[1024], sB[1024];
  int t = threadIdx.x;
  int v = (t < len) ? bsums[t] : 0;
  sA[t] = v;
  __syncthreads();
  int* src = sA;
  int* dst = sB;
  for (int off = 1; off < 1024; off <<= 1) {
    int x = src[t];
    if (t >= off) x += src[t - off];
    dst[t] = x;
    __syncthreads();
    int* tmp = src; src = dst; dst = tmp;
  }
  if (t < len) bsums[t] = src[t] - v;  // exclusive
}

// rowptr = starts, cursor = ENDS (kspmm rowend)
__global__ void kscan3(const int* __restrict__ deg, const int* __restrict__ bsums,
                       int* __restrict__ rowptr, int* __restrict__ cursor) {
  __shared__ int sA[256], sB[256];
  int t = threadIdx.x;
  int i0 = blockIdx.x * 512 + t * 2;
  int a = deg[i0], b = deg[i0 + 1];
  int s = a + b;
  sA[t] = s;
  __syncthreads();
  int* src = sA;
  int* dst = sB;
  for (int off = 1; off < 256; off <<= 1) {
    int x = src[t];
    if (t >= off) x += src[t - off];
    dst[t] = x;
    __syncthreads();
    int* tmp = src; src = dst; dst = tmp;
  }
  int excl = src[t] - s;
  int r0 = bsums[blockIdx.x] + excl;
  rowptr[i0] = r0;
  rowptr[i0 + 1] = r0 + a;
  cursor[i0] = r0 + a;          // end of row i0
  cursor[i0 + 1] = r0 + a + b;  // end of row i0+1
}

// ---------------- deterministic radix partition (no global atomics) -------

// per-block LDS histogram over NB = n/128 buckets; cnts[b][k] contiguous.
__global__ void kphist(const int* __restrict__ rows, int* __restrict__ cnts,
                       int NB, int chunk) {
  __shared__ int cnt[4096];
  int t = threadIdx.x, b = blockIdx.x;
  for (int k = t; k < NB; k += 256) cnt[k] = 0;
  __syncthreads();
  int base = b * chunk;
  for (int i = t; i < chunk; i += 256) atomicAdd(&cnt[rows[base + i] >> 7], 1);
  __syncthreads();
  for (int k = t; k < NB; k += 256) cnts[(size_t)b * NB + k] = cnt[k];
}

// per-bucket exclusive scan over the kNCH blocks (1 WG per bucket)
__global__ void kpscan1(int* __restrict__ cnts, int NB) {
  __shared__ int sA[256], sB[256];
  int k = blockIdx.x, t = threadIdx.x;
  int v = cnts[(size_t)t * NB + k];
  sA[t] = v;
  __syncthreads();
  int* src = sA;
  int* dst = sB;
  for (int off = 1; off < 256; off <<= 1) {
    int x = src[t];
    if (t >= off) x += src[t - off];
    dst[t] = x;
    __syncthreads();
    int* tm = src; src = dst; dst = tm;
  }
  cnts[(size_t)t * NB + k] = src[t] - v;  // exclusive over blocks
}

// scatter edges to bucket-major tmp using LDS cursors seeded from
// rowptr[k*128] + per-block prefix. payload = (row&127)<<22 | e  (e < 2^22).
__global__ void kpscatter(const int* __restrict__ rows, const int* __restrict__ cnts,
                          const int* __restrict__ rowptr, int* __restrict__ tmp,
                          int NB, int chunk) {
  __shared__ int cur[4096];
  int t = threadIdx.x, b = blockIdx.x;
  for (int k = t; k < NB; k += 256)
    cur[k] = rowptr[k << 7] + cnts[(size_t)b * NB + k];
  __syncthreads();
  int base = b * chunk;
  for (int i = t; i < chunk; i += 256) {
    int e = base + i;
    int r = rows[e];
    int p = atomicAdd(&cur[r >> 7], 1);
    tmp[p] = ((r & 127) << 22) | e;
  }
}

// one WG per 128-row bucket; per-row cursors in LDS; scatter ei within the
// bucket's ~4KB CSR window (line-local writes, no global atomics).
__global__ void kplace(const int* __restrict__ tmp, const int* __restrict__ rowptr,
                       int* __restrict__ ei, int NB, int E) {
  __shared__ int lcur[128];
  int b = blockIdx.x, t = threadIdx.x;
  int rbase = b << 7;
  if (t < 128) lcur[t] = rowptr[rbase + t];
  __syncthreads();
  int segStart = rowptr[rbase];
  int segEnd = (b == NB - 1) ? E : rowptr[rbase + 128];
  for (int p = segStart + t; p < segEnd; p += 256) {
    int pk = tmp[p];
    int pos = atomicAdd(&lcur[pk >> 22], 1);
    ei[pos] = pk & 0x3FFFFF;
  }
}

// ---------------- dense / sparse passes (single branch) ----------------

// Z = X @ W^T   (X: n x 32, W: 32 x 32), no bias
__global__ void kproj(const float* __restrict__ X, const float* __restrict__ W,
                      float* __restrict__ Z) {
  __shared__ float w[1024];
  for (int k = threadIdx.x; k < 1024; k += 256) w[k] = W[k];
  __syncthreads();
  int i = blockIdx.x * 256 + threadIdx.x;
  float x[32];
  const float4* xp = (const float4*)(X + (size_t)i * 32);
#pragma unroll
  for (int q = 0; q < 8; q++) {
    float4 t = xp[q];
    x[4 * q] = t.x; x[4 * q + 1] = t.y; x[4 * q + 2] = t.z; x[4 * q + 3] = t.w;
  }
  float z[32];
#pragma unroll
  for (int o = 0; o < 32; o++) {
    float a = 0.f;
#pragma unroll
    for (int f = 0; f < 32; f++) a += w[o * 32 + f] * x[f];
    z[o] = a;
  }
  float4* zr = (float4*)(Z + (size_t)i * 32);
#pragma unroll
  for (int q = 0; q < 8; q++)
    zr[q] = make_float4(z[4 * q], z[4 * q + 1], z[4 * q + 2], z[4 * q + 3]);
}

// H[i] = sum_p vals[ei] * Z[cols[ei]]   (CSR gather; rows with deg 0 -> 0)
__global__ void kspmm(const int* __restrict__ ei, const int* __restrict__ cols,
                      const float* __restrict__ vals, const int* __restrict__ rowptr,
                      const int* __restrict__ rowend, const float* __restrict__ Z,
                      float* __restrict__ H) {
  int gi = blockIdx.x * 256 + threadIdx.x;
  int s = rowptr[gi], e = rowend[gi];
  float acc[32];
#pragma unroll
  for (int j = 0; j < 32; j++) acc[j] = 0.f;
  for (int p = s; p < e; p++) {
    int ed = ei[p];
    int c = cols[ed];
    float v = vals[ed];
    const float4* zr = (const float4*)(Z + (size_t)c * 32);
#pragma unroll
    for (int q = 0; q < 8; q++) {
      float4 t = zr[q];
      acc[4 * q] += v * t.x; acc[4 * q + 1] += v * t.y;
      acc[4 * q + 2] += v * t.z; acc[4 * q + 3] += v * t.w;
    }
  }
  float4* hr = (float4*)(H + (size_t)gi * 32);
#pragma unroll
  for (int q = 0; q < 8; q++)
    hr[q] = make_float4(acc[4 * q], acc[4 * q + 1], acc[4 * q + 2], acc[4 * q + 3]);
}

// H += b (store biased h_l); S[g][o] += h @ Wl[o, 32l:32l+32]; cnt[g] += 1 (l==0)
// LDS per-graph partials (batch sorted => block spans few graphs); fallback to
// direct global atomics if a block spans >8 graphs.
__global__ void kpost(float* __restrict__ H, const float* __restrict__ b,
                      const float* __restrict__ Wl, int l,
                      const int* __restrict__ batch, float* __restrict__ S,
                      float* __restrict__ cnt, int docnt) {
  __shared__ float w[320];      // w[o*32+j] = Wl[o][32l+j]
  __shared__ float bb[32];
  __shared__ float part[8][10];
  __shared__ int pcnt[8];
  __shared__ int g0s;
  int t = threadIdx.x;
  for (int k = t; k < 320; k += 256)
    w[k] = Wl[(k / 32) * 96 + 32 * l + (k % 32)];
  if (t < 32) bb[t] = b[t];
  if (t < 80) part[t / 10][t % 10] = 0.f;
  if (t < 8) pcnt[t] = 0;
  if (t == 0) g0s = batch[blockIdx.x * 256];
  __syncthreads();
  int g0 = g0s;
  int i = blockIdx.x * 256 + t;
  int g = batch[i];
  float4* hp = (float4*)(H + (size_t)i * 32);
  float h[32];
#pragma unroll
  for (int q = 0; q < 8; q++) {
    float4 tq = hp[q];
    h[4 * q] = tq.x + bb[4 * q];         h[4 * q + 1] = tq.y + bb[4 * q + 1];
    h[4 * q + 2] = tq.z + bb[4 * q + 2]; h[4 * q + 3] = tq.w + bb[4 * q + 3];
    hp[q] = make_float4(h[4 * q], h[4 * q + 1], h[4 * q + 2], h[4 * q + 3]);
  }
  float r[10];
#pragma unroll
  for (int o = 0; o < 10; o++) {
    float a = 0.f;
#pragma unroll
    for (int j = 0; j < 32; j++) a += w[o * 32 + j] * h[j];
    r[o] = a;
  }
  int gl = g - g0;
  if (gl >= 0 && gl < 8) {
#pragma unroll
    for (int o = 0; o < 10; o++) atomicAdd(&part[gl][o], r[o]);
    if (docnt) atomicAdd(&pcnt[gl], 1);
  } else {
#pragma unroll
    for (int o = 0; o < 10; o++) atomAddF(&S[(size_t)g * 10 + o], r[o]);
    if (docnt) atomAddF(&cnt[g], 1.f);
  }
  __syncthreads();
  if (t < 80) {
    int gl2 = t / 10, o = t % 10;
    int gg = g0 + gl2;
    float v = part[gl2][o];
    if (gg < kG && v != 0.f) atomAddF(&S[(size_t)gg * 10 + o], v);
  }
  if (docnt && t < 8) {
    int gg = g0 + t;
    if (gg < kG && pcnt[t] > 0) atomAddF(&cnt[gg], (float)pcnt[t]);
  }
}

// Z = leaky(H) @ W^T  (row-local; overwrites Z in place)
__global__ void kmid(const float* __restrict__ H, const float* __restrict__ W,
                     float* __restrict__ Z) {
  __shared__ float w[1024];
  for (int k = threadIdx.x; k < 1024; k += 256) w[k] = W[k];
  __syncthreads();
  int i = blockIdx.x * 256 + threadIdx.x;
  float h[32];
  const float4* hp = (const float4*)(H + (size_t)i * 32);
#pragma unroll
  for (int q = 0; q < 8; q++) {
    float4 t = hp[q];
    h[4 * q] = t.x; h[4 * q + 1] = t.y; h[4 * q + 2] = t.z; h[4 * q + 3] = t.w;
  }
#pragma unroll
  for (int j = 0; j < 32; j++) h[j] = (h[j] >= 0.f) ? h[j] : 0.01f * h[j];
  float z[32];
#pragma unroll
  for (int o = 0; o < 32; o++) {
    float a = 0.f;
#pragma unroll
    for (int f = 0; f < 32; f++) a += w[o * 32 + f] * h[f];
    z[o] = a;
  }
  float4* zr = (float4*)(Z + (size_t)i * 32);
#pragma unroll
  for (int q = 0; q < 8; q++)
    zr[q] = make_float4(z[4 * q], z[4 * q + 1], z[4 * q + 2], z[4 * q + 3]);
}

// out = softmax(concat(S_b / max(cnt_b,1)) @ Wc^T + bc)   Wc: (10,30)
__global__ void kfinal(const float* __restrict__ S, const float* __restrict__ cnt,
                       const float* __restrict__ Wc, const float* __restrict__ bc,
                       float* __restrict__ out) {
  int g = threadIdx.x;  // 512 threads, one per graph
  float o[30];
#pragma unroll
  for (int s = 0; s < 3; s++) {
    float c = cnt[s * kG + g];
    float inv = 1.f / fmaxf(c, 1.f);
#pragma unroll
    for (int j = 0; j < 10; j++)
      o[s * 10 + j] = S[((size_t)s * kG + g) * 10 + j] * inv;
  }
  float z[10];
  float m = -1e30f;
#pragma unroll
  for (int k = 0; k < 10; k++) {
    float t = bc[k];
    for (int j = 0; j < 30; j++) t += Wc[k * 30 + j] * o[j];
    z[k] = t;
    m = fmaxf(m, t);
  }
  float sum = 0.f;
#pragma unroll
  for (int k = 0; k < 10; k++) { z[k] = expf(z[k] - m); sum += z[k]; }
  float r = 1.f / sum;
#pragma unroll
  for (int k = 0; k < 10; k++) out[(size_t)g * 10 + k] = z[k] * r;
}

extern "C" void kernel_launch(void* const* d_in, const int* in_sizes, int n_in,
                              void* d_out, int out_size, void* d_ws, size_t ws_size,
                              hipStream_t stream) {
  const int nb[3] = {262144, 524288, 131072};
  const int eb[3] = {2097152, 4194304, 1048576};

  const int* rowsv[3] = {(const int*)d_in[0], (const int*)d_in[5], (const int*)d_in[10]};
  const int* colsv[3] = {(const int*)d_in[1], (const int*)d_in[6], (const int*)d_in[11]};
  const float* valsv[3] = {(const float*)d_in[2], (const float*)d_in[7], (const float*)d_in[12]};
  const float* Xv[3] = {(const float*)d_in[3], (const float*)d_in[8], (const float*)d_in[13]};
  const int* batchv[3] = {(const int*)d_in[4], (const int*)d_in[9], (const int*)d_in[14]};
  // per-branch weights: W1,b1,W2,b2,W3,b3,Wl,bl at [15..22], [23..30], [31..38]
  const float* W1v[3] = {(const float*)d_in[15], (const float*)d_in[23], (const float*)d_in[31]};
  const float* B1v[3] = {(const float*)d_in[16], (const float*)d_in[24], (const float*)d_in[32]};
  const float* W2v[3] = {(const float*)d_in[17], (const float*)d_in[25], (const float*)d_in[33]};
  const float* B2v[3] = {(const float*)d_in[18], (const float*)d_in[26], (const float*)d_in[34]};
  const float* W3v[3] = {(const float*)d_in[19], (const float*)d_in[27], (const float*)d_in[35]};
  const float* B3v[3] = {(const float*)d_in[20], (const float*)d_in[28], (const float*)d_in[36]};
  const float* Wlv[3] = {(const float*)d_in[21], (const float*)d_in[29], (const float*)d_in[37]};
  const float* Wc = (const float*)d_in[39];
  const float* bc = (const float*)d_in[40];

  char* ws = (char*)d_ws;
  int* rowptr = (int*)(ws + OFF_RP);
  int* cursor = (int*)(ws + OFF_CUR);
  int* deg = (int*)(ws + OFF_DEG);
  int* bsums = (int*)(ws + OFF_BS);
  int* ei = (int*)(ws + OFF_EI);
  float* Z = (float*)(ws + OFF_Z);
  float* H = (float*)(ws + OFF_H);
  float* S = (float*)(ws + OFF_S);
  float* cnt = (float*)(ws + OFF_CNT);
  float* out = (float*)d_out;

  hipMemsetAsync(S, 0, (size_t)3 * kG * 10 * 4 + (size_t)3 * kG * 4, stream);

  for (int b = 0; b < 3; b++) {
    const int n = nb[b], e = eb[b];
    const int NB = n / 128;         // radix buckets (<=4096)
    const int chunk = e / kNCH;     // edges per partition block
    const float* Bl[3] = {B1v[b], B2v[b], B3v[b]};
    const float* Wmid[2] = {W2v[b], W3v[b]};
    int* tmp = (int*)(ws + OFF_H);   // H region idle during CSR build
    int* cnts = (int*)(ws + OFF_Z);  // Z region idle during CSR build (<=4MB)

    // row-level degree + scan -> rowptr (starts), cursor (ends)
    hipMemsetAsync(deg, 0, (size_t)n * 4, stream);
    khist<<<e / 256, 256, 0, stream>>>(rowsv[b], deg);
    kscan1<<<n / 512, 256, 0, stream>>>(deg, bsums);
    kscan2<<<1, 1024, 0, stream>>>(bsums, n / 512);
    kscan3<<<n / 512, 256, 0, stream>>>(deg, bsums, rowptr, cursor);

    // deterministic partition into bucket-major tmp, then place into ei
    kphist<<<kNCH, 256, 0, stream>>>(rowsv[b], cnts, NB, chunk);
    kpscan1<<<NB, 256, 0, stream>>>(cnts, NB);
    kpscatter<<<kNCH, 256, 0, stream>>>(rowsv[b], cnts, rowptr, tmp, NB, chunk);
    kplace<<<NB, 256, 0, stream>>>(tmp, rowptr, ei, NB, e);

    // layer 1 projection
    kproj<<<n / 256, 256, 0, stream>>>(Xv[b], W1v[b], Z);

    for (int l = 0; l < 3; l++) {
      kspmm<<<n / 256, 256, 0, stream>>>(ei, colsv[b], valsv[b], rowptr, cursor, Z, H);
      kpost<<<n / 256, 256, 0, stream>>>(H, Bl[l], Wlv[b], l, batchv[b],
                                         S + (size_t)b * kG * 10, cnt + b * kG,
                                         l == 0 ? 1 : 0);
      if (l < 2)
        kmid<<<n / 256, 256, 0, stream>>>(H, Wmid[l], Z);
    }
  }

  kfinal<<<1, 512, 0, stream>>>(S, cnt, Wc, bc, out);
}